// Round 2
// baseline (175.400 us; speedup 1.0000x reference)
//
#include <hip/hip_runtime.h>

#define DIMN 64
#define NNB 16
#define NREL 33
#define WPB 4   // batch elements (waves) per block

__device__ __forceinline__ float bcastf(float x, int lane) {
    return __int_as_float(__builtin_amdgcn_readlane(__float_as_int(x), lane));
}

__global__ __launch_bounds__(64 * WPB, 4)
void kgs_kernel(const int* __restrict__ u, const int* __restrict__ v,
                const int* __restrict__ adj, const int* __restrict__ rel_adj,
                const float* __restrict__ usr_emb, const float* __restrict__ ent_emb,
                const float* __restrict__ rel_emb,
                const float* __restrict__ W0, const float* __restrict__ b0,
                const float* __restrict__ W1, const float* __restrict__ b1,
                float* __restrict__ out, int B)
{
    const int tid = threadIdx.x;
    const int wid = tid >> 6;                 // wave in block = batch elem
    const int d   = tid & 63;                 // lane = output dim
    int b = blockIdx.x * WPB + wid;
    if (b >= B) b = B - 1;                    // duplicate work, same value written
    const int n16 = d & 15;

    __shared__ __align__(16) float user_sh[WPB][DIMN];
    __shared__ float ur_sh[WPB][NREL + 7];    // ur[r] = dot(user, rel_emb[r])

    const int uu = u[b];
    const int vv = v[b];

    const float user_d = usr_emb[uu * DIMN + d];
    user_sh[wid][d] = user_d;
    __syncthreads();

    // ---- 33 user·rel dots: collapses every attention score to a table lookup
    if (d < NREL) {
        const float* re = rel_emb + d * DIMN;
        float acc = 0.f;
        #pragma unroll
        for (int k = 0; k < DIMN; k += 4) {
            const float4 uk = *(const float4*)(&user_sh[wid][k]);
            const float4 rk = *(const float4*)(re + k);
            acc = fmaf(uk.x, rk.x, acc);
            acc = fmaf(uk.y, rk.y, acc);
            acc = fmaf(uk.z, rk.z, acc);
            acc = fmaf(uk.w, rk.w, acc);
        }
        ur_sh[wid][d] = acc;
    }
    __syncthreads();

    const int e1n = adj[vv * NNB + n16];      // hop-1 neighbor ids (slot = d&15)
    const int r1n = rel_adj[vv * NNB + n16];
    const float b0d = b0[d];

    float sv_r[NNB];   // ent_emb rows of hop-1 entities (wave-private, registers)
    float xs[NNB];     // sv + agg, inputs to the batched matmul

    // ================= iter 0, hop 1: gather + attention for all 16 m =========
    #pragma unroll
    for (int m = 0; m < NNB; ++m) {
        const int em = __builtin_amdgcn_readlane(e1n, m);   // uniform entity id
        const float sv = ent_emb[em * DIMN + d];

        const int e2n = adj[em * NNB + n16];
        const int r2n = rel_adj[em * NNB + n16];

        // softmax over 16 neighbors (no max-sub: |score| << 88)
        const float e = __expf(ur_sh[wid][r2n]);
        float sum = e;
        sum += __shfl_xor(sum, 1);
        sum += __shfl_xor(sum, 2);
        sum += __shfl_xor(sum, 4);
        sum += __shfl_xor(sum, 8);
        const float attn = e * __builtin_amdgcn_rcpf(sum);

        float agg = 0.f;
        #pragma unroll
        for (int n = 0; n < NNB; ++n) {
            const int en = __builtin_amdgcn_readlane(e2n, n);
            agg = fmaf(bcastf(attn, n), ent_emb[en * DIMN + d], agg);
        }
        sv_r[m] = sv;
        xs[m]   = sv + agg;
    }

    // ================= batched matmul: [16,64] @ W0, 16 independent accums ====
    float o[NNB];
    #pragma unroll
    for (int m = 0; m < NNB; ++m) o[m] = b0d;

    #pragma unroll 4
    for (int k = 0; k < DIMN; ++k) {
        const float wk = W0[k * DIMN + d];    // scalar base + lane offset
        #pragma unroll
        for (int m = 0; m < NNB; ++m)
            o[m] = fmaf(bcastf(xs[m], k), wk, o[m]);
    }

    float h1[NNB];
    #pragma unroll
    for (int m = 0; m < NNB; ++m)
        h1[m] = 1.f / (1.f + __expf(-o[m]));

    // ================= hop-0 attention (shared by iter0 and iter1) ============
    const float sv0 = ent_emb[vv * DIMN + d];
    const float e0 = __expf(ur_sh[wid][r1n]);
    float sum0 = e0;
    sum0 += __shfl_xor(sum0, 1);
    sum0 += __shfl_xor(sum0, 2);
    sum0 += __shfl_xor(sum0, 4);
    sum0 += __shfl_xor(sum0, 8);
    const float attn0 = e0 * __builtin_amdgcn_rcpf(sum0);

    float agg0 = 0.f, agg1 = 0.f;
    #pragma unroll
    for (int n = 0; n < NNB; ++n) {
        const float an = bcastf(attn0, n);
        agg0 = fmaf(an, sv_r[n], agg0);       // iter0/hop0: raw neighbor vecs
        agg1 = fmaf(an, h1[n],  agg1);        // iter1/hop0: hop-1 outputs
    }

    // ---- iter0/hop0: sigmoid((sv0+agg0) @ W0 + b0)
    const float x0 = sv0 + agg0;
    {
        float a0 = 0.f, a1 = 0.f, a2 = 0.f, a3 = 0.f;
        for (int k = 0; k < DIMN; k += 4) {
            const float* wr = W0 + k * DIMN;
            a0 = fmaf(bcastf(x0, k + 0), wr[d], a0);
            a1 = fmaf(bcastf(x0, k + 1), wr[DIMN + d], a1);
            a2 = fmaf(bcastf(x0, k + 2), wr[2 * DIMN + d], a2);
            a3 = fmaf(bcastf(x0, k + 3), wr[3 * DIMN + d], a3);
        }
        const float o0 = b0d + ((a0 + a1) + (a2 + a3));
        const float h0 = 1.f / (1.f + __expf(-o0));

        // ---- iter1/hop0: tanh((h0+agg1) @ W1 + b1)
        const float x1 = h0 + agg1;
        float c0 = 0.f, c1 = 0.f, c2 = 0.f, c3 = 0.f;
        for (int k = 0; k < DIMN; k += 4) {
            const float* wr = W1 + k * DIMN;
            c0 = fmaf(bcastf(x1, k + 0), wr[d], c0);
            c1 = fmaf(bcastf(x1, k + 1), wr[DIMN + d], c1);
            c2 = fmaf(bcastf(x1, k + 2), wr[2 * DIMN + d], c2);
            c3 = fmaf(bcastf(x1, k + 3), wr[3 * DIMN + d], c3);
        }
        const float o1 = b1[d] + ((c0 + c1) + (c2 + c3));
        const float item_d = 1.f - 2.f / (1.f + __expf(2.f * o1));  // tanh

        // ---- final: sigmoid(user . item)
        float p = user_d * item_d;
        p += __shfl_xor(p, 1);
        p += __shfl_xor(p, 2);
        p += __shfl_xor(p, 4);
        p += __shfl_xor(p, 8);
        p += __shfl_xor(p, 16);
        p += __shfl_xor(p, 32);
        if (d == 0) out[b] = 1.f / (1.f + __expf(-p));
    }
}

extern "C" void kernel_launch(void* const* d_in, const int* in_sizes, int n_in,
                              void* d_out, int out_size, void* d_ws, size_t ws_size,
                              hipStream_t stream) {
    const int*   u       = (const int*)d_in[0];
    const int*   v       = (const int*)d_in[1];
    const int*   adj     = (const int*)d_in[2];
    const int*   rel_adj = (const int*)d_in[3];
    const float* usr_emb = (const float*)d_in[4];
    const float* ent_emb = (const float*)d_in[5];
    const float* rel_emb = (const float*)d_in[6];
    const float* W0      = (const float*)d_in[7];
    const float* b0      = (const float*)d_in[8];
    const float* W1      = (const float*)d_in[9];
    const float* b1      = (const float*)d_in[10];
    float* out = (float*)d_out;

    const int B = in_sizes[0];   // 4096
    const int grid = (B + WPB - 1) / WPB;
    kgs_kernel<<<dim3(grid), dim3(64 * WPB), 0, stream>>>(u, v, adj, rel_adj, usr_emb,
                                                          ent_emb, rel_emb, W0, b0, W1, b1,
                                                          out, B);
}

// Round 3
// 160.431 us; speedup vs baseline: 1.0933x; 1.0933x over previous
//
#include <hip/hip_runtime.h>

#define DIMN 64
#define NNB 16
#define NREL 33
#define WPB 4          // batch elements (waves) per block
#define XSTR 68        // LDS tile row stride in floats (pad: 2-way banks = free)

typedef float  floatx4 __attribute__((ext_vector_type(4)));
typedef short  shortx8 __attribute__((ext_vector_type(8)));

__device__ __forceinline__ float bcastf(float x, int lane) {
    return __int_as_float(__builtin_amdgcn_readlane(__float_as_int(x), lane));
}

// ---- prep: split W0 (fp32 64x64) into bf16 hi/lo MFMA B-fragments in d_ws ----
// frag f = kstep*4 + t  (kstep: K 0..31 / 32..63, t: N-tile of 16 cols)
// B-frag lane l holds B[k = kstep*32 + (l>>4)*8 + j][n = t*16 + (l&15)], j=0..7
// ws layout (ushort): hi[f][lane][8] at (f*64+l)*8 ; lo at 4096 + same
__global__ void prep_w0_frags(const float* __restrict__ W0, unsigned short* __restrict__ wsp) {
    const int tid = blockIdx.x * blockDim.x + threadIdx.x;   // 0..511
    if (tid >= 512) return;
    const int l = tid & 63;
    const int t = (tid >> 6) & 3;
    const int ks = tid >> 8;
    const int k0 = ks * 32 + (l >> 4) * 8;
    const int n  = t * 16 + (l & 15);
    const unsigned base = ((unsigned)(ks * 4 + t) * 64 + l) * 8;
    #pragma unroll
    for (int j = 0; j < 8; ++j) {
        const float x = W0[(k0 + j) * DIMN + n];
        const unsigned u  = __float_as_uint(x);
        const unsigned uh = u & 0xFFFF0000u;
        const float lf = x - __uint_as_float(uh);       // exact residual
        wsp[base + j]        = (unsigned short)(u >> 16);
        wsp[4096 + base + j] = (unsigned short)(__float_as_uint(lf) >> 16);
    }
}

__global__ __launch_bounds__(64 * WPB, 4)
void kgs_kernel(const int* __restrict__ u, const int* __restrict__ v,
                const int* __restrict__ adj, const int* __restrict__ rel_adj,
                const float* __restrict__ usr_emb, const float* __restrict__ ent_emb,
                const float* __restrict__ rel_emb,
                const float* __restrict__ W0, const float* __restrict__ b0,
                const float* __restrict__ W1, const float* __restrict__ b1,
                const unsigned short* __restrict__ wsp,
                float* __restrict__ out, int B)
{
    const int tid = threadIdx.x;
    const int wid = tid >> 6;
    const int d   = tid & 63;
    int b = blockIdx.x * WPB + wid;
    if (b >= B) b = B - 1;
    const int n16 = d & 15;

    // ALL LDS is wave-private (indexed by wid) -> zero __syncthreads in kernel:
    // no barrier ever drains our prefetch vmcnt queue.
    __shared__ __align__(16) float user_sh[WPB][DIMN];
    __shared__ float ur_sh[WPB][NREL + 7];
    __shared__ __align__(16) float xbuf[WPB][NNB * XSTR];   // xs tile, reused for h1

    const int uu = u[b];
    const int vv = v[b];

    const float user_d = usr_emb[uu * DIMN + d];
    const int e1n = adj[vv * NNB + n16];
    const int r1n = rel_adj[vv * NNB + n16];
    user_sh[wid][d] = user_d;

    // ---- 33 user-rel dots (collapses all attention scores to lookups); same-wave LDS
    if (d < NREL) {
        const float* re = rel_emb + d * DIMN;
        float acc = 0.f;
        #pragma unroll
        for (int k = 0; k < DIMN; k += 4) {
            const float4 uk = *(const float4*)(&user_sh[wid][k]);
            const float4 rk = *(const float4*)(re + k);
            acc = fmaf(uk.x, rk.x, acc);
            acc = fmaf(uk.y, rk.y, acc);
            acc = fmaf(uk.z, rk.z, acc);
            acc = fmaf(uk.w, rk.w, acc);
        }
        ur_sh[wid][d] = acc;
    }

    // ---- upfront prefetch: 48 independent loads into force-live arrays (MLP)
    float sv_r[NNB];
    int   e2n_r[NNB], r2n_r[NNB];
    #pragma unroll
    for (int m = 0; m < NNB; ++m) {
        const int em = __builtin_amdgcn_readlane(e1n, m);
        sv_r[m]  = ent_emb[(size_t)em * DIMN + d];
        e2n_r[m] = adj[em * NNB + n16];
        r2n_r[m] = rel_adj[em * NNB + n16];
    }

    // ---- softmax per m (no max-sub: scores far from overflow)
    float attn[NNB];
    #pragma unroll
    for (int m = 0; m < NNB; ++m) {
        const float e = __expf(ur_sh[wid][r2n_r[m]]);
        float s = e;
        s += __shfl_xor(s, 1);
        s += __shfl_xor(s, 2);
        s += __shfl_xor(s, 4);
        s += __shfl_xor(s, 8);
        attn[m] = e * __builtin_amdgcn_rcpf(s);
    }

    // ---- hop-2 gather + aggregate (16 independent fma chains, scalar row bases)
    float agg[NNB];
    #pragma unroll
    for (int m = 0; m < NNB; ++m) agg[m] = 0.f;
    #pragma unroll
    for (int m = 0; m < NNB; ++m) {
        #pragma unroll
        for (int n = 0; n < NNB; ++n) {
            const int en = __builtin_amdgcn_readlane(e2n_r[m], n);
            const float* rp = ent_emb + (size_t)en * DIMN;
            agg[m] = fmaf(bcastf(attn[m], n), rp[d], agg[m]);
        }
    }

    // ---- xs tile -> wave-private LDS (lane d writes column d of row m)
    #pragma unroll
    for (int m = 0; m < NNB; ++m)
        xbuf[wid][m * XSTR + d] = sv_r[m] + agg[m];

    // ---- A-fragments: lane holds A[m=d&15][k=(d>>4)*8+j], bf16 hi/lo split
    shortx8 Ahi[2], Alo[2];
    #pragma unroll
    for (int ks = 0; ks < 2; ++ks) {
        const float* ar = &xbuf[wid][(d & 15) * XSTR + ((d >> 4) * 8) + ks * 32];
        const floatx4 xa = *(const floatx4*)ar;
        const floatx4 xb = *(const floatx4*)(ar + 4);
        unsigned uh[8], ul[8];
        #pragma unroll
        for (int j = 0; j < 8; ++j) {
            const float x = (j < 4) ? xa[j] : xb[j - 4];
            const unsigned ub = __float_as_uint(x);
            uh[j] = ub & 0xFFFF0000u;
            ul[j] = __float_as_uint(x - __uint_as_float(uh[j]));
        }
        union { int i[4]; shortx8 s; } ch, cl;
        #pragma unroll
        for (int p = 0; p < 4; ++p) {
            ch.i[p] = (int)(uh[2 * p + 1] | (uh[2 * p] >> 16));
            cl.i[p] = (int)((ul[2 * p + 1] & 0xFFFF0000u) | (ul[2 * p] >> 16));
        }
        Ahi[ks] = ch.s;
        Alo[ks] = cl.s;
    }

    // ---- MFMA: O = Xhi*Whi + Xhi*Wlo + Xlo*Whi  (fp32-accurate 3-term)
    const shortx8* wf = (const shortx8*)wsp;
    floatx4 acc[4];
    #pragma unroll
    for (int t = 0; t < 4; ++t) acc[t] = (floatx4){0.f, 0.f, 0.f, 0.f};
    #pragma unroll
    for (int t = 0; t < 4; ++t) {
        #pragma unroll
        for (int ks = 0; ks < 2; ++ks) {
            const int f = ks * 4 + t;
            const shortx8 bhi = wf[f * 64 + d];
            const shortx8 blo = wf[512 + f * 64 + d];
            acc[t] = __builtin_amdgcn_mfma_f32_16x16x32_bf16(Ahi[ks], bhi, acc[t], 0, 0, 0);
            acc[t] = __builtin_amdgcn_mfma_f32_16x16x32_bf16(Ahi[ks], blo, acc[t], 0, 0, 0);
            acc[t] = __builtin_amdgcn_mfma_f32_16x16x32_bf16(Alo[ks], bhi, acc[t], 0, 0, 0);
        }
    }

    // ---- bias + sigmoid in D-layout (row=(d>>4)*4+reg, col=16t+(d&15)) -> LDS
    #pragma unroll
    for (int t = 0; t < 4; ++t) {
        const float bv = b0[t * 16 + (d & 15)];
        #pragma unroll
        for (int reg = 0; reg < 4; ++reg) {
            const float o = acc[t][reg] + bv;
            const float h = 1.f / (1.f + __expf(-o));
            const int m = (d >> 4) * 4 + reg;
            xbuf[wid][m * XSTR + t * 16 + (d & 15)] = h;
        }
    }
    // back to lane-d layout
    float h1_r[NNB];
    #pragma unroll
    for (int n = 0; n < NNB; ++n)
        h1_r[n] = xbuf[wid][n * XSTR + d];

    // ================= hop-0 attention (shared by iter0 and iter1) ============
    const float sv0 = ent_emb[(size_t)vv * DIMN + d];
    const float e0 = __expf(ur_sh[wid][r1n]);
    float sum0 = e0;
    sum0 += __shfl_xor(sum0, 1);
    sum0 += __shfl_xor(sum0, 2);
    sum0 += __shfl_xor(sum0, 4);
    sum0 += __shfl_xor(sum0, 8);
    const float attn0 = e0 * __builtin_amdgcn_rcpf(sum0);

    float agg0 = 0.f, agg1 = 0.f;
    #pragma unroll
    for (int n = 0; n < NNB; ++n) {
        const float an = bcastf(attn0, n);
        agg0 = fmaf(an, sv_r[n], agg0);
        agg1 = fmaf(an, h1_r[n], agg1);
    }

    // ---- iter0/hop0: sigmoid((sv0+agg0) @ W0 + b0)
    const float x0 = sv0 + agg0;
    float a0 = 0.f, a1 = 0.f, a2 = 0.f, a3 = 0.f;
    for (int k = 0; k < DIMN; k += 4) {
        const float* wr = W0 + k * DIMN;
        a0 = fmaf(bcastf(x0, k + 0), wr[d], a0);
        a1 = fmaf(bcastf(x0, k + 1), wr[DIMN + d], a1);
        a2 = fmaf(bcastf(x0, k + 2), wr[2 * DIMN + d], a2);
        a3 = fmaf(bcastf(x0, k + 3), wr[3 * DIMN + d], a3);
    }
    const float o0 = b0[d] + ((a0 + a1) + (a2 + a3));
    const float h0 = 1.f / (1.f + __expf(-o0));

    // ---- iter1/hop0: tanh((h0+agg1) @ W1 + b1)
    const float x1 = h0 + agg1;
    float c0 = 0.f, c1 = 0.f, c2 = 0.f, c3 = 0.f;
    for (int k = 0; k < DIMN; k += 4) {
        const float* wr = W1 + k * DIMN;
        c0 = fmaf(bcastf(x1, k + 0), wr[d], c0);
        c1 = fmaf(bcastf(x1, k + 1), wr[DIMN + d], c1);
        c2 = fmaf(bcastf(x1, k + 2), wr[2 * DIMN + d], c2);
        c3 = fmaf(bcastf(x1, k + 3), wr[3 * DIMN + d], c3);
    }
    const float o1 = b1[d] + ((c0 + c1) + (c2 + c3));
    const float item_d = 1.f - 2.f / (1.f + __expf(2.f * o1));  // tanh

    // ---- final: sigmoid(user . item)
    float p = user_d * item_d;
    p += __shfl_xor(p, 1);
    p += __shfl_xor(p, 2);
    p += __shfl_xor(p, 4);
    p += __shfl_xor(p, 8);
    p += __shfl_xor(p, 16);
    p += __shfl_xor(p, 32);
    if (d == 0) out[b] = 1.f / (1.f + __expf(-p));
}

extern "C" void kernel_launch(void* const* d_in, const int* in_sizes, int n_in,
                              void* d_out, int out_size, void* d_ws, size_t ws_size,
                              hipStream_t stream) {
    const int*   u       = (const int*)d_in[0];
    const int*   v       = (const int*)d_in[1];
    const int*   adj     = (const int*)d_in[2];
    const int*   rel_adj = (const int*)d_in[3];
    const float* usr_emb = (const float*)d_in[4];
    const float* ent_emb = (const float*)d_in[5];
    const float* rel_emb = (const float*)d_in[6];
    const float* W0      = (const float*)d_in[7];
    const float* b0      = (const float*)d_in[8];
    const float* W1      = (const float*)d_in[9];
    const float* b1      = (const float*)d_in[10];
    float* out = (float*)d_out;
    unsigned short* wsp = (unsigned short*)d_ws;

    const int B = in_sizes[0];   // 4096
    prep_w0_frags<<<dim3(2), dim3(256), 0, stream>>>(W0, wsp);
    const int grid = (B + WPB - 1) / WPB;
    kgs_kernel<<<dim3(grid), dim3(64 * WPB), 0, stream>>>(u, v, adj, rel_adj, usr_emb,
                                                          ent_emb, rel_emb, W0, b0, W1, b1,
                                                          wsp, out, B);
}